// Round 8
// baseline (178.888 us; speedup 1.0000x reference)
//
#include <hip/hip_runtime.h>
#include <hip/hip_bf16.h>

#define B_SZ   2
#define H_SZ   48
#define W_SZ   48
#define L_SZ   2304          // H*W
#define CIN    768           // C_INNER
#define KG     4
#define DI     192           // D_IN (channels per direction)
#define NS     16            // N_STATE
#define RR     12            // R_RANK
#define XD     44            // RR + 2*NS
#define MTOK   4608          // B*L
#define CL     16            // scan chunk length
#define NC     144           // L / CL

typedef __attribute__((ext_vector_type(8))) short short8;
typedef __attribute__((ext_vector_type(4))) float f32x4;

__device__ inline ushort f2b(float f) {
    uint u = __builtin_bit_cast(uint, f);
    u = (u + 0x7FFF + ((u >> 16) & 1)) >> 16;   // RNE to bf16
    return (ushort)u;
}
__device__ inline float b2f(ushort b) {
    uint u = ((uint)b) << 16;
    return __builtin_bit_cast(float, u);
}
__device__ inline short8 f2b8(float4 a, float4 b) {
    short8 r;
    r[0] = (short)f2b(a.x); r[1] = (short)f2b(a.y);
    r[2] = (short)f2b(a.z); r[3] = (short)f2b(a.w);
    r[4] = (short)f2b(b.x); r[5] = (short)f2b(b.y);
    r[6] = (short)f2b(b.z); r[7] = (short)f2b(b.w);
    return r;
}

// ---------------------------------------------------------------------------
// Software grid barrier (device scope). Requires all blocks co-resident —
// guaranteed at launch time via occupancy query + fallback path.
// ---------------------------------------------------------------------------
__device__ inline void gridbar(uint* bar, uint nb) {
    __syncthreads();
    if (threadIdx.x == 0) {
        uint g = __hip_atomic_load(&bar[1], __ATOMIC_RELAXED, __HIP_MEMORY_SCOPE_AGENT);
        uint a = __hip_atomic_fetch_add(&bar[0], 1u, __ATOMIC_ACQ_REL, __HIP_MEMORY_SCOPE_AGENT);
        if (a == nb - 1u) {
            __hip_atomic_store(&bar[0], 0u, __ATOMIC_RELAXED, __HIP_MEMORY_SCOPE_AGENT);
            __hip_atomic_store(&bar[1], g + 1u, __ATOMIC_RELEASE, __HIP_MEMORY_SCOPE_AGENT);
        } else {
            while (__hip_atomic_load(&bar[1], __ATOMIC_ACQUIRE, __HIP_MEMORY_SCOPE_AGENT) == g) {
                __builtin_amdgcn_s_sleep(8);
            }
        }
    }
    __syncthreads();
}

// ---------------------------------------------------------------------------
// MFMA GEMM, generalized tiles: C[M,N] = A[M,K] * Bw[N,K]^T, K-step 64.
// TM in {64,128}, TN in {32,64}. 4 waves stacked on M.
// ---------------------------------------------------------------------------
template<int TM, int TN, bool ABF, bool CBF>
__global__ __launch_bounds__(256) void gemm_tn(
        const void* __restrict__ Av, const float* __restrict__ Bw,
        void* __restrict__ Cv, int M, int N, int K) {
    __shared__ ushort As[TM][72];
    __shared__ ushort Bs[TN][72];
    constexpr int MF   = TM / 64;    // M fragments per wave
    constexpr int NF   = TN / 16;    // N fragments
    constexpr int ANUM = TM / 32;    // short8 loads/thread for A
    constexpr int BNUM = TN / 32;    // short8 loads/thread for B
    const int tid  = threadIdx.x;
    const int lane = tid & 63;
    const int wave = tid >> 6;
    const int wrow = wave * (MF * 16);
    const int bm = blockIdx.y * TM, bn = blockIdx.x * TN;
    const int frow = lane & 15;
    const int fk   = (lane >> 4) * 8;
    const int orow = (lane >> 4) * 4;

    f32x4 acc[MF][NF] = {};

    for (int k0 = 0; k0 < K; k0 += 64) {
        short8 aval[ANUM];
#pragma unroll
        for (int i = 0; i < ANUM; ++i) {
            int idx = tid + i * 256;
            int row = idx >> 3, q = idx & 7;
            if (ABF) {
                aval[i] = *(const short8*)&((const ushort*)Av)[(size_t)(bm + row) * K + k0 + q * 8];
            } else {
                const float* ap = &((const float*)Av)[(size_t)(bm + row) * K + k0 + q * 8];
                aval[i] = f2b8(*(const float4*)ap, *(const float4*)(ap + 4));
            }
        }
        short8 bval[BNUM];
#pragma unroll
        for (int i = 0; i < BNUM; ++i) {
            int idx = tid + i * 256;
            int row = idx >> 3, q = idx & 7;
            const float* bp = &Bw[(size_t)(bn + row) * K + k0 + q * 8];
            bval[i] = f2b8(*(const float4*)bp, *(const float4*)(bp + 4));
        }

        __syncthreads();
#pragma unroll
        for (int i = 0; i < ANUM; ++i) {
            int idx = tid + i * 256;
            *(short8*)&As[idx >> 3][(idx & 7) * 8] = aval[i];
        }
#pragma unroll
        for (int i = 0; i < BNUM; ++i) {
            int idx = tid + i * 256;
            *(short8*)&Bs[idx >> 3][(idx & 7) * 8] = bval[i];
        }
        __syncthreads();

#pragma unroll
        for (int hf = 0; hf < 2; ++hf) {
            short8 af[MF], bf[NF];
#pragma unroll
            for (int mi = 0; mi < MF; ++mi)
                af[mi] = *(const short8*)&As[wrow + mi * 16 + frow][hf * 32 + fk];
#pragma unroll
            for (int ni = 0; ni < NF; ++ni)
                bf[ni] = *(const short8*)&Bs[ni * 16 + frow][hf * 32 + fk];
#pragma unroll
            for (int mi = 0; mi < MF; ++mi)
#pragma unroll
                for (int ni = 0; ni < NF; ++ni)
                    acc[mi][ni] = __builtin_amdgcn_mfma_f32_16x16x32_bf16(
                                      af[mi], bf[ni], acc[mi][ni], 0, 0, 0);
        }
    }

#pragma unroll
    for (int mi = 0; mi < MF; ++mi) {
        int rbase = bm + wrow + mi * 16 + orow;
#pragma unroll
        for (int ni = 0; ni < NF; ++ni) {
            int col = bn + ni * 16 + frow;
#pragma unroll
            for (int r = 0; r < 4; ++r) {
                if (CBF)
                    ((ushort*)Cv)[(size_t)(rbase + r) * N + col] = f2b(acc[mi][ni][r]);
                else
                    ((float*)Cv)[(size_t)(rbase + r) * N + col] = acc[mi][ni][r];
            }
        }
    }
}

// ---------------------------------------------------------------------------
// Depthwise 3x3 conv + bias + SiLU, 8 channels/thread, vectorized.
// ---------------------------------------------------------------------------
__global__ __launch_bounds__(256) void conv_silu_scatter(
        const ushort* __restrict__ xzb, const float* __restrict__ cw,
        const float* __restrict__ cb, ushort* __restrict__ xsb) {
    int g = blockIdx.x * 256 + threadIdx.x;     // 442368 total
    int c8 = g % 96;
    int pos = g / 96;
    int w = pos % W_SZ;
    int h = (pos / W_SZ) % H_SZ;
    int b = pos / (W_SZ * H_SZ);
    int c0 = c8 * 8;

    float wt[72];
    const float* cwp = &cw[c0 * 9];
#pragma unroll
    for (int i = 0; i < 18; ++i) {
        float4 v = *(const float4*)(cwp + i * 4);
        wt[i * 4 + 0] = v.x; wt[i * 4 + 1] = v.y;
        wt[i * 4 + 2] = v.z; wt[i * 4 + 3] = v.w;
    }
    float acc[8];
#pragma unroll
    for (int j = 0; j < 8; ++j) acc[j] = cb[c0 + j];

#pragma unroll
    for (int dh = -1; dh <= 1; ++dh) {
        int hh = h + dh;
        if (hh < 0 || hh >= H_SZ) continue;
#pragma unroll
        for (int dw = -1; dw <= 1; ++dw) {
            int ww = w + dw;
            if (ww < 0 || ww >= W_SZ) continue;
            int tap = (dh + 1) * 3 + (dw + 1);
            short8 xv = *(const short8*)&xzb[(size_t)((b * H_SZ + hh) * W_SZ + ww) * CIN + c0];
#pragma unroll
            for (int j = 0; j < 8; ++j)
                acc[j] = fmaf(b2f((ushort)xv[j]), wt[j * 9 + tap], acc[j]);
        }
    }

    float s[8];
#pragma unroll
    for (int j = 0; j < 8; ++j)
        s[j] = acc[j] * __builtin_amdgcn_rcpf(1.f + __expf(-acc[j]));   // SiLU

    int k = c0 / DI, d = c0 % DI;
    int lrow = h * W_SZ + w;
    int lcol = w * H_SZ + h;
    int l;
    if      (k == 0) l = lrow;
    else if (k == 1) l = lcol;
    else if (k == 2) l = L_SZ - 1 - lrow;
    else             l = L_SZ - 1 - lcol;
    float4 lo = {s[0], s[1], s[2], s[3]}, hi = {s[4], s[5], s[6], s[7]};
    *(short8*)&xsb[(size_t)((b * KG + k) * L_SZ + l) * DI + d] = f2b8(lo, hi);
}

// ---------------------------------------------------------------------------
// MFMA fused x-projection + dt-projection (32-token tiles, 384 threads).
// ---------------------------------------------------------------------------
__global__ __launch_bounds__(384) void xproj_dt_mfma(
        const ushort* __restrict__ xsb, const float* __restrict__ xpw,
        const float* __restrict__ dtw, const float* __restrict__ dtb,
        float* __restrict__ xdbl, ushort* __restrict__ dts_b) {
    __shared__ ushort Ws[48][200];
    __shared__ ushort Wd[192][40];
    __shared__ ushort dsh[32][40];

    const int tid  = threadIdx.x;
    const int lane = tid & 63;
    const int wave = tid >> 6;        // 0..5
    const int bm = blockIdx.x * 32;
    const int bk = blockIdx.y;
    const int k  = bk & 3;
    const int frow = lane & 15;
    const int fk   = (lane >> 4) * 8;
    const int orow = (lane >> 4) * 4;
    const int rg = wave & 1;
    const int cg = wave >> 1;

#pragma unroll
    for (int i = 0; i < 6; ++i) {
        int idx = tid + i * 384;
        int row = idx / 48, g = idx % 48;
        ushort4 u = {0, 0, 0, 0};
        if (row < XD) {
            float4 v = *(const float4*)&xpw[((size_t)(k * XD) + row) * 192 + g * 4];
            u.x = f2b(v.x); u.y = f2b(v.y); u.z = f2b(v.z); u.w = f2b(v.w);
        }
        *(ushort4*)&Ws[row][g * 4] = u;
    }
#pragma unroll
    for (int i = 0; i < 3; ++i) {
        int idx = tid + i * 384;
        if (idx < 960) {
            float4 z = {0.f, 0.f, 0.f, 0.f};
            *(float4*)&Wd[idx / 5][(idx % 5) * 8] = z;
        } else if (idx < 1120) {
            int j = idx - 960;
            float4 z = {0.f, 0.f, 0.f, 0.f};
            *(float4*)&dsh[j / 5][(j % 5) * 8] = z;
        }
    }
    __syncthreads();

#pragma unroll
    for (int i = 0; i < 6; ++i) {
        int idx = tid + i * 384;
        int row = idx / RR, c = idx % RR;
        Wd[row][c] = f2b(dtw[((size_t)(k * DI) + row) * RR + c]);
    }

    f32x4 acc1 = {};
    const ushort* arow = &xsb[(size_t)(bk * L_SZ + bm + rg * 16 + frow) * DI];
#pragma unroll
    for (int k0 = 0; k0 < 192; k0 += 32) {
        short8 af = *(const short8*)&arow[k0 + fk];
        short8 bv = *(const short8*)&Ws[cg * 16 + frow][k0 + fk];
        acc1 = __builtin_amdgcn_mfma_f32_16x16x32_bf16(af, bv, acc1, 0, 0, 0);
    }

    {
        int col = cg * 16 + frow;
#pragma unroll
        for (int r = 0; r < 4; ++r) {
            float v = acc1[r];
            int row = rg * 16 + orow + r;
            if (col >= RR && col < XD)
                xdbl[(size_t)(bk * L_SZ + bm + row) * XD + col] = v;
            if (cg == 0 && col < RR)
                dsh[row][col] = f2b(v);
        }
    }
    __syncthreads();

#pragma unroll
    for (int t = 0; t < 2; ++t) {
        int d = (wave * 2 + t) * 16 + frow;
        short8 bv = *(const short8*)&Wd[d][fk];
        float bias = dtb[k * DI + d];
#pragma unroll
        for (int rg2 = 0; rg2 < 2; ++rg2) {
            short8 af2 = *(const short8*)&dsh[rg2 * 16 + frow][fk];
            f32x4 a2 = {};
            a2 = __builtin_amdgcn_mfma_f32_16x16x32_bf16(af2, bv, a2, 0, 0, 0);
#pragma unroll
            for (int r = 0; r < 4; ++r) {
                float a = a2[r] + bias;
                float sp = fmaxf(a, 0.f) + __logf(1.f + __expf(-fabsf(a)));
                dts_b[(size_t)(bk * L_SZ + bm + rg2 * 16 + orow + r) * DI + d] = f2b(sp);
            }
        }
    }
}

// ---------------------------------------------------------------------------
// FUSED three-pass scan in ONE kernel via software grid barrier.
// ---------------------------------------------------------------------------
__global__ __launch_bounds__(192, 4) void scan_fused(
        const ushort* __restrict__ dts_b, const ushort* __restrict__ xsb,
        const float* __restrict__ xdbl, const float* __restrict__ A_logs,
        float* __restrict__ Ebuf, float* __restrict__ Sbuf,
        float* __restrict__ Pbuf, float* __restrict__ Hstart,
        const float* __restrict__ Ds, ushort* __restrict__ ypre_b,
        uint* __restrict__ bar) {
    const int blk = blockIdx.x;
    const int bk = blk / NC, ch = blk % NC;
    const int d = threadIdx.x, k = bk % KG, b = bk / KG;
    const int l0 = ch * CL;

    __shared__ float bsh[CL][NS];
    __shared__ float csh[CL][NS];
    for (int t = threadIdx.x; t < CL * NS; t += 192) {
        int l = t / NS, n = t % NS;
        const float* row = &xdbl[(size_t)(bk * L_SZ + l0 + l) * XD];
        bsh[l][n] = row[RR + n];
        csh[l][n] = row[RR + NS + n];
    }
    __syncthreads();

    // ---------------- phase A ---------------------------------------------
    {
        float Aa[NS], S[NS];
        const float* ar = &A_logs[(size_t)(k * DI + d) * NS];
        bool fast = true;
#pragma unroll
        for (int n = 0; n < NS; ++n) {
            Aa[n] = -__expf(ar[n]);
            S[n] = 0.f;
            fast = fast && (fabsf(Aa[n] + (float)(n + 1)) < 1e-4f * (n + 1));
        }
        float* sp = &Sbuf[(size_t)((bk * NC + ch) * DI + d) * NS];
        if (fast) {
            float P = 1.f;
#pragma unroll
            for (int l = 0; l < CL; ++l) {
                float dt = b2f(dts_b[(size_t)(bk * L_SZ + l0 + l) * DI + d]);
                float u  = b2f(xsb [(size_t)(bk * L_SZ + l0 + l) * DI + d]);
                float du = dt * u;
                float4 b0 = *(const float4*)&bsh[l][0];
                float4 b1 = *(const float4*)&bsh[l][4];
                float4 b2 = *(const float4*)&bsh[l][8];
                float4 b3 = *(const float4*)&bsh[l][12];
                float Bv[NS] = {b0.x,b0.y,b0.z,b0.w, b1.x,b1.y,b1.z,b1.w,
                                b2.x,b2.y,b2.z,b2.w, b3.x,b3.y,b3.z,b3.w};
                float e1 = __expf(-dt);
                P *= e1;
                float e = e1;
                S[0] = fmaf(S[0], e, du * Bv[0]);
#pragma unroll
                for (int n = 1; n < NS; ++n) {
                    e *= e1;
                    S[n] = fmaf(S[n], e, du * Bv[n]);
                }
            }
            Pbuf[(size_t)(bk * NC + ch) * DI + d] = P;
#pragma unroll
            for (int q = 0; q < 4; ++q) {
                float4 v = {S[q*4], S[q*4+1], S[q*4+2], S[q*4+3]};
                *(float4*)&sp[q * 4] = v;
            }
        } else {
            float E[NS];
#pragma unroll
            for (int n = 0; n < NS; ++n) E[n] = 1.f;
#pragma unroll 8
            for (int l = 0; l < CL; ++l) {
                float dt = b2f(dts_b[(size_t)(bk * L_SZ + l0 + l) * DI + d]);
                float u  = b2f(xsb [(size_t)(bk * L_SZ + l0 + l) * DI + d]);
                float du = dt * u;
                float4 b0 = *(const float4*)&bsh[l][0];
                float4 b1 = *(const float4*)&bsh[l][4];
                float4 b2 = *(const float4*)&bsh[l][8];
                float4 b3 = *(const float4*)&bsh[l][12];
                float Bv[NS] = {b0.x,b0.y,b0.z,b0.w, b1.x,b1.y,b1.z,b1.w,
                                b2.x,b2.y,b2.z,b2.w, b3.x,b3.y,b3.z,b3.w};
#pragma unroll
                for (int n = 0; n < NS; ++n) {
                    float e = __expf(dt * Aa[n]);
                    E[n] *= e;
                    S[n] = fmaf(S[n], e, du * Bv[n]);
                }
            }
            Pbuf[(size_t)(bk * NC + ch) * DI + d] = -1.f;
            float* ep = &Ebuf[(size_t)((bk * NC + ch) * DI + d) * NS];
#pragma unroll
            for (int q = 0; q < 4; ++q) {
                float4 ve = {E[q*4], E[q*4+1], E[q*4+2], E[q*4+3]};
                float4 vs = {S[q*4], S[q*4+1], S[q*4+2], S[q*4+3]};
                *(float4*)&ep[q * 4] = ve;
                *(float4*)&sp[q * 4] = vs;
            }
        }
    }

    gridbar(bar, gridDim.x);

    // ---------------- phase B (first 6144 threads) ------------------------
    {
        constexpr int P = 8;
        int t = blk * 192 + threadIdx.x;
        if (t < 8 * DI * 4) {
            int bkB = t / (DI * 4);
            int dn = (t % (DI * 4)) * 4;
            int dB = dn >> 4;
            int n0 = dn & 15;
            const size_t stride = (size_t)DI * NS;
            size_t off = (size_t)(bkB * NC) * stride + dn;
            const float* pb = &Pbuf[(size_t)(bkB * NC) * DI + dB];

            float4 h = {0.f, 0.f, 0.f, 0.f};
            bool fastu = (pb[0] >= 0.f);

            if (fastu) {
                float  pA[P], pB2[P];
                float4 sA[P], sB[P];
                size_t offL = off;
                int    cP   = 0;
#pragma unroll
                for (int j = 0; j < P; ++j) {
                    pA[j] = pb[(size_t)(cP + j) * DI];
                    sA[j] = *(const float4*)&Sbuf[offL + (size_t)j * stride];
                }
                offL += (size_t)P * stride; cP += P;

                for (int c = 0; c < NC; c += 2 * P) {
#pragma unroll
                    for (int j = 0; j < P; ++j) {
                        pB2[j] = pb[(size_t)(cP + j) * DI];
                        sB[j] = *(const float4*)&Sbuf[offL + (size_t)j * stride];
                    }
                    offL += (size_t)P * stride; cP += P;

#pragma unroll
                    for (int j = 0; j < P; ++j) {
                        *(float4*)&Hstart[off + (size_t)j * stride] = h;
                        float Pv = pA[j];
                        float P2 = Pv * Pv, P3 = P2 * Pv;
                        float P4 = P2 * P2, P8 = P4 * P4;
                        float base = Pv * ((n0 & 4) ? P4 : 1.f) * ((n0 & 8) ? P8 : 1.f);
                        h.x = fmaf(base,      h.x, sA[j].x);
                        h.y = fmaf(base * Pv, h.y, sA[j].y);
                        h.z = fmaf(base * P2, h.z, sA[j].z);
                        h.w = fmaf(base * P3, h.w, sA[j].w);
                    }
                    off += (size_t)P * stride;

                    if (c + 2 * P < NC) {
#pragma unroll
                        for (int j = 0; j < P; ++j) {
                            pA[j] = pb[(size_t)(cP + j) * DI];
                            sA[j] = *(const float4*)&Sbuf[offL + (size_t)j * stride];
                        }
                    }
                    offL += (size_t)P * stride; cP += P;

#pragma unroll
                    for (int j = 0; j < P; ++j) {
                        *(float4*)&Hstart[off + (size_t)j * stride] = h;
                        float Pv = pB2[j];
                        float P2 = Pv * Pv, P3 = P2 * Pv;
                        float P4 = P2 * P2, P8 = P4 * P4;
                        float base = Pv * ((n0 & 4) ? P4 : 1.f) * ((n0 & 8) ? P8 : 1.f);
                        h.x = fmaf(base,      h.x, sB[j].x);
                        h.y = fmaf(base * Pv, h.y, sB[j].y);
                        h.z = fmaf(base * P2, h.z, sB[j].z);
                        h.w = fmaf(base * P3, h.w, sB[j].w);
                    }
                    off += (size_t)P * stride;
                }
            } else {
                float4 eA[P], sA[P], eB[P], sB[P];
                size_t offL = off;
#pragma unroll
                for (int j = 0; j < P; ++j) {
                    eA[j] = *(const float4*)&Ebuf[offL + (size_t)j * stride];
                    sA[j] = *(const float4*)&Sbuf[offL + (size_t)j * stride];
                }
                offL += (size_t)P * stride;

                for (int c = 0; c < NC; c += 2 * P) {
#pragma unroll
                    for (int j = 0; j < P; ++j) {
                        eB[j] = *(const float4*)&Ebuf[offL + (size_t)j * stride];
                        sB[j] = *(const float4*)&Sbuf[offL + (size_t)j * stride];
                    }
                    offL += (size_t)P * stride;

#pragma unroll
                    for (int j = 0; j < P; ++j) {
                        *(float4*)&Hstart[off + (size_t)j * stride] = h;
                        h.x = fmaf(eA[j].x, h.x, sA[j].x);
                        h.y = fmaf(eA[j].y, h.y, sA[j].y);
                        h.z = fmaf(eA[j].z, h.z, sA[j].z);
                        h.w = fmaf(eA[j].w, h.w, sA[j].w);
                    }
                    off += (size_t)P * stride;

                    if (c + 2 * P < NC) {
#pragma unroll
                        for (int j = 0; j < P; ++j) {
                            eA[j] = *(const float4*)&Ebuf[offL + (size_t)j * stride];
                            sA[j] = *(const float4*)&Sbuf[offL + (size_t)j * stride];
                        }
                    }
                    offL += (size_t)P * stride;

#pragma unroll
                    for (int j = 0; j < P; ++j) {
                        *(float4*)&Hstart[off + (size_t)j * stride] = h;
                        h.x = fmaf(eB[j].x, h.x, sB[j].x);
                        h.y = fmaf(eB[j].y, h.y, sB[j].y);
                        h.z = fmaf(eB[j].z, h.z, sB[j].z);
                        h.w = fmaf(eB[j].w, h.w, sB[j].w);
                    }
                    off += (size_t)P * stride;
                }
            }
        }
    }

    gridbar(bar, gridDim.x);

    // ---------------- phase C ---------------------------------------------
    {
        float Aa[NS], h[NS];
        const float* ar = &A_logs[(size_t)(k * DI + d) * NS];
        const float* hp = &Hstart[(size_t)((bk * NC + ch) * DI + d) * NS];
        bool fast = true;
#pragma unroll
        for (int n = 0; n < NS; ++n) {
            Aa[n] = -__expf(ar[n]);
            h[n] = hp[n];
            fast = fast && (fabsf(Aa[n] + (float)(n + 1)) < 1e-4f * (n + 1));
        }
        float Dd = Ds[k * DI + d];

#pragma unroll 8
        for (int l = 0; l < CL; ++l) {
            float dt = b2f(dts_b[(size_t)(bk * L_SZ + l0 + l) * DI + d]);
            float u  = b2f(xsb [(size_t)(bk * L_SZ + l0 + l) * DI + d]);
            float du = dt * u;
            float4 b0 = *(const float4*)&bsh[l][0];
            float4 b1 = *(const float4*)&bsh[l][4];
            float4 b2 = *(const float4*)&bsh[l][8];
            float4 b3 = *(const float4*)&bsh[l][12];
            float Bv[NS] = {b0.x,b0.y,b0.z,b0.w, b1.x,b1.y,b1.z,b1.w,
                            b2.x,b2.y,b2.z,b2.w, b3.x,b3.y,b3.z,b3.w};
            float4 c0 = *(const float4*)&csh[l][0];
            float4 c1 = *(const float4*)&csh[l][4];
            float4 c2 = *(const float4*)&csh[l][8];
            float4 c3 = *(const float4*)&csh[l][12];
            float Cv[NS] = {c0.x,c0.y,c0.z,c0.w, c1.x,c1.y,c1.z,c1.w,
                            c2.x,c2.y,c2.z,c2.w, c3.x,c3.y,c3.z,c3.w};
            float p[NS];
            if (fast) {
                float e1 = __expf(-dt);
                float e = e1;
                h[0] = fmaf(h[0], e, du * Bv[0]);
                p[0] = h[0] * Cv[0];
#pragma unroll
                for (int n = 1; n < NS; ++n) {
                    e *= e1;
                    h[n] = fmaf(h[n], e, du * Bv[n]);
                    p[n] = h[n] * Cv[n];
                }
            } else {
#pragma unroll
                for (int n = 0; n < NS; ++n) {
                    float e = __expf(dt * Aa[n]);
                    h[n] = fmaf(h[n], e, du * Bv[n]);
                    p[n] = h[n] * Cv[n];
                }
            }
#pragma unroll
            for (int s = 8; s >= 1; s >>= 1)
#pragma unroll
                for (int n = 0; n < 8; ++n)
                    if (n < s) p[n] = p[n] + p[n + s];
            float y = fmaf(Dd, u, p[0]);

            int lg = l0 + l;
            int pos;
            if      (k == 0) pos = lg;
            else if (k == 1) pos = (lg % H_SZ) * W_SZ + (lg / H_SZ);
            else if (k == 2) pos = L_SZ - 1 - lg;
            else { int j = L_SZ - 1 - lg; pos = (j % H_SZ) * W_SZ + (j / H_SZ); }
            ypre_b[(size_t)(b * L_SZ + pos) * CIN + k * DI + d] = f2b(y);
        }
    }
}

// ---------------------------------------------------------------------------
// Fallback separate scan kernels (proven round-6 versions).
// ---------------------------------------------------------------------------
__global__ __launch_bounds__(192) void scan_passA(
        const ushort* __restrict__ dts_b, const ushort* __restrict__ xsb,
        const float* __restrict__ xdbl, const float* __restrict__ A_logs,
        float* __restrict__ Ebuf, float* __restrict__ Sbuf,
        float* __restrict__ Pbuf) {
    int blk = blockIdx.x;
    int bk = blk / NC, ch = blk % NC;
    int d = threadIdx.x, k = bk % KG;
    int l0 = ch * CL;

    __shared__ float bsh[CL][NS];
    for (int t = threadIdx.x; t < CL * NS; t += 192) {
        int l = t / NS, n = t % NS;
        bsh[l][n] = xdbl[(size_t)(bk * L_SZ + l0 + l) * XD + RR + n];
    }
    __syncthreads();

    float Aa[NS], S[NS];
    const float* ar = &A_logs[(size_t)(k * DI + d) * NS];
    bool fast = true;
#pragma unroll
    for (int n = 0; n < NS; ++n) {
        Aa[n] = -__expf(ar[n]);
        S[n] = 0.f;
        fast = fast && (fabsf(Aa[n] + (float)(n + 1)) < 1e-4f * (n + 1));
    }

    float* sp = &Sbuf[(size_t)((bk * NC + ch) * DI + d) * NS];
    if (fast) {
        float P = 1.f;
#pragma unroll
        for (int l = 0; l < CL; ++l) {
            float dt = b2f(dts_b[(size_t)(bk * L_SZ + l0 + l) * DI + d]);
            float u  = b2f(xsb [(size_t)(bk * L_SZ + l0 + l) * DI + d]);
            float du = dt * u;
            float4 b0 = *(const float4*)&bsh[l][0];
            float4 b1 = *(const float4*)&bsh[l][4];
            float4 b2 = *(const float4*)&bsh[l][8];
            float4 b3 = *(const float4*)&bsh[l][12];
            float Bv[NS] = {b0.x,b0.y,b0.z,b0.w, b1.x,b1.y,b1.z,b1.w,
                            b2.x,b2.y,b2.z,b2.w, b3.x,b3.y,b3.z,b3.w};
            float e1 = __expf(-dt);
            P *= e1;
            float e = e1;
            S[0] = fmaf(S[0], e, du * Bv[0]);
#pragma unroll
            for (int n = 1; n < NS; ++n) {
                e *= e1;
                S[n] = fmaf(S[n], e, du * Bv[n]);
            }
        }
        Pbuf[(size_t)(bk * NC + ch) * DI + d] = P;
#pragma unroll
        for (int q = 0; q < 4; ++q) {
            float4 v = {S[q*4], S[q*4+1], S[q*4+2], S[q*4+3]};
            *(float4*)&sp[q * 4] = v;
        }
    } else {
        float E[NS];
#pragma unroll
        for (int n = 0; n < NS; ++n) E[n] = 1.f;
#pragma unroll 8
        for (int l = 0; l < CL; ++l) {
            float dt = b2f(dts_b[(size_t)(bk * L_SZ + l0 + l) * DI + d]);
            float u  = b2f(xsb [(size_t)(bk * L_SZ + l0 + l) * DI + d]);
            float du = dt * u;
            float4 b0 = *(const float4*)&bsh[l][0];
            float4 b1 = *(const float4*)&bsh[l][4];
            float4 b2 = *(const float4*)&bsh[l][8];
            float4 b3 = *(const float4*)&bsh[l][12];
            float Bv[NS] = {b0.x,b0.y,b0.z,b0.w, b1.x,b1.y,b1.z,b1.w,
                            b2.x,b2.y,b2.z,b2.w, b3.x,b3.y,b3.z,b3.w};
#pragma unroll
            for (int n = 0; n < NS; ++n) {
                float e = __expf(dt * Aa[n]);
                E[n] *= e;
                S[n] = fmaf(S[n], e, du * Bv[n]);
            }
        }
        Pbuf[(size_t)(bk * NC + ch) * DI + d] = -1.f;
        float* ep = &Ebuf[(size_t)((bk * NC + ch) * DI + d) * NS];
#pragma unroll
        for (int q = 0; q < 4; ++q) {
            float4 ve = {E[q*4], E[q*4+1], E[q*4+2], E[q*4+3]};
            float4 vs = {S[q*4], S[q*4+1], S[q*4+2], S[q*4+3]};
            *(float4*)&ep[q * 4] = ve;
            *(float4*)&sp[q * 4] = vs;
        }
    }
}

__global__ __launch_bounds__(64) void scan_passB(
        const float* __restrict__ Ebuf, const float* __restrict__ Sbuf,
        const float* __restrict__ Pbuf, float* __restrict__ Hstart) {
    constexpr int P = 8;
    int t = blockIdx.x * 64 + threadIdx.x;
    int bk = t / (DI * 4);
    int dn = (t % (DI * 4)) * 4;
    int d  = dn >> 4;
    int n0 = dn & 15;
    const size_t stride = (size_t)DI * NS;
    size_t off  = (size_t)(bk * NC) * stride + dn;
    const float* pb = &Pbuf[(size_t)(bk * NC) * DI + d];

    float4 h = {0.f, 0.f, 0.f, 0.f};
    bool fastu = (pb[0] >= 0.f);

    if (fastu) {
        float  pA[P], pB[P];
        float4 sA[P], sB[P];
        size_t offL = off;
        int    cP   = 0;
#pragma unroll
        for (int j = 0; j < P; ++j) {
            pA[j] = pb[(size_t)(cP + j) * DI];
            sA[j] = *(const float4*)&Sbuf[offL + (size_t)j * stride];
        }
        offL += (size_t)P * stride; cP += P;

        for (int c = 0; c < NC; c += 2 * P) {
#pragma unroll
            for (int j = 0; j < P; ++j) {
                pB[j] = pb[(size_t)(cP + j) * DI];
                sB[j] = *(const float4*)&Sbuf[offL + (size_t)j * stride];
            }
            offL += (size_t)P * stride; cP += P;

#pragma unroll
            for (int j = 0; j < P; ++j) {
                *(float4*)&Hstart[off + (size_t)j * stride] = h;
                float Pv = pA[j];
                float P2 = Pv * Pv, P3 = P2 * Pv;
                float P4 = P2 * P2, P8 = P4 * P4;
                float base = Pv * ((n0 & 4) ? P4 : 1.f) * ((n0 & 8) ? P8 : 1.f);
                h.x = fmaf(base,      h.x, sA[j].x);
                h.y = fmaf(base * Pv, h.y, sA[j].y);
                h.z = fmaf(base * P2, h.z, sA[j].z);
                h.w = fmaf(base * P3, h.w, sA[j].w);
            }
            off += (size_t)P * stride;

            if (c + 2 * P < NC) {
#pragma unroll
                for (int j = 0; j < P; ++j) {
                    pA[j] = pb[(size_t)(cP + j) * DI];
                    sA[j] = *(const float4*)&Sbuf[offL + (size_t)j * stride];
                }
            }
            offL += (size_t)P * stride; cP += P;

#pragma unroll
            for (int j = 0; j < P; ++j) {
                *(float4*)&Hstart[off + (size_t)j * stride] = h;
                float Pv = pB[j];
                float P2 = Pv * Pv, P3 = P2 * Pv;
                float P4 = P2 * P2, P8 = P4 * P4;
                float base = Pv * ((n0 & 4) ? P4 : 1.f) * ((n0 & 8) ? P8 : 1.f);
                h.x = fmaf(base,      h.x, sB[j].x);
                h.y = fmaf(base * Pv, h.y, sB[j].y);
                h.z = fmaf(base * P2, h.z, sB[j].z);
                h.w = fmaf(base * P3, h.w, sB[j].w);
            }
            off += (size_t)P * stride;
        }
    } else {
        float4 eA[P], sA[P], eB[P], sB[P];
        size_t offL = off;
#pragma unroll
        for (int j = 0; j < P; ++j) {
            eA[j] = *(const float4*)&Ebuf[offL + (size_t)j * stride];
            sA[j] = *(const float4*)&Sbuf[offL + (size_t)j * stride];
        }
        offL += (size_t)P * stride;

        for (int c = 0; c < NC; c += 2 * P) {
#pragma unroll
            for (int j = 0; j < P; ++j) {
                eB[j] = *(const float4*)&Ebuf[offL + (size_t)j * stride];
                sB[j] = *(const float4*)&Sbuf[offL + (size_t)j * stride];
            }
            offL += (size_t)P * stride;

#pragma unroll
            for (int j = 0; j < P; ++j) {
                *(float4*)&Hstart[off + (size_t)j * stride] = h;
                h.x = fmaf(eA[j].x, h.x, sA[j].x);
                h.y = fmaf(eA[j].y, h.y, sA[j].y);
                h.z = fmaf(eA[j].z, h.z, sA[j].z);
                h.w = fmaf(eA[j].w, h.w, sA[j].w);
            }
            off += (size_t)P * stride;

            if (c + 2 * P < NC) {
#pragma unroll
                for (int j = 0; j < P; ++j) {
                    eA[j] = *(const float4*)&Ebuf[offL + (size_t)j * stride];
                    sA[j] = *(const float4*)&Sbuf[offL + (size_t)j * stride];
                }
            }
            offL += (size_t)P * stride;

#pragma unroll
            for (int j = 0; j < P; ++j) {
                *(float4*)&Hstart[off + (size_t)j * stride] = h;
                h.x = fmaf(eB[j].x, h.x, sB[j].x);
                h.y = fmaf(eB[j].y, h.y, sB[j].y);
                h.z = fmaf(eB[j].z, h.z, sB[j].z);
                h.w = fmaf(eB[j].w, h.w, sB[j].w);
            }
            off += (size_t)P * stride;
        }
    }
}

__global__ __launch_bounds__(192) void scan_passC(
        const ushort* __restrict__ dts_b, const ushort* __restrict__ xsb,
        const float* __restrict__ xdbl, const float* __restrict__ A_logs,
        const float* __restrict__ Hstart, const float* __restrict__ Ds,
        ushort* __restrict__ ypre_b) {
    int blk = blockIdx.x;
    int bk = blk / NC, ch = blk % NC;
    int d = threadIdx.x, k = bk % KG, b = bk / KG;
    int l0 = ch * CL;

    __shared__ float bsh[CL][NS];
    __shared__ float csh[CL][NS];
    for (int t = threadIdx.x; t < CL * NS; t += 192) {
        int l = t / NS, n = t % NS;
        const float* row = &xdbl[(size_t)(bk * L_SZ + l0 + l) * XD];
        bsh[l][n] = row[RR + n];
        csh[l][n] = row[RR + NS + n];
    }
    __syncthreads();

    float Aa[NS], h[NS];
    const float* ar = &A_logs[(size_t)(k * DI + d) * NS];
    const float* hp = &Hstart[(size_t)((bk * NC + ch) * DI + d) * NS];
    bool fast = true;
#pragma unroll
    for (int n = 0; n < NS; ++n) {
        Aa[n] = -__expf(ar[n]);
        h[n] = hp[n];
        fast = fast && (fabsf(Aa[n] + (float)(n + 1)) < 1e-4f * (n + 1));
    }
    float Dd = Ds[k * DI + d];

#pragma unroll 8
    for (int l = 0; l < CL; ++l) {
        float dt = b2f(dts_b[(size_t)(bk * L_SZ + l0 + l) * DI + d]);
        float u  = b2f(xsb [(size_t)(bk * L_SZ + l0 + l) * DI + d]);
        float du = dt * u;
        float4 b0 = *(const float4*)&bsh[l][0];
        float4 b1 = *(const float4*)&bsh[l][4];
        float4 b2 = *(const float4*)&bsh[l][8];
        float4 b3 = *(const float4*)&bsh[l][12];
        float Bv[NS] = {b0.x,b0.y,b0.z,b0.w, b1.x,b1.y,b1.z,b1.w,
                        b2.x,b2.y,b2.z,b2.w, b3.x,b3.y,b3.z,b3.w};
        float4 c0 = *(const float4*)&csh[l][0];
        float4 c1 = *(const float4*)&csh[l][4];
        float4 c2 = *(const float4*)&csh[l][8];
        float4 c3 = *(const float4*)&csh[l][12];
        float Cv[NS] = {c0.x,c0.y,c0.z,c0.w, c1.x,c1.y,c1.z,c1.w,
                        c2.x,c2.y,c2.z,c2.w, c3.x,c3.y,c3.z,c3.w};
        float p[NS];
        if (fast) {
            float e1 = __expf(-dt);
            float e = e1;
            h[0] = fmaf(h[0], e, du * Bv[0]);
            p[0] = h[0] * Cv[0];
#pragma unroll
            for (int n = 1; n < NS; ++n) {
                e *= e1;
                h[n] = fmaf(h[n], e, du * Bv[n]);
                p[n] = h[n] * Cv[n];
            }
        } else {
#pragma unroll
            for (int n = 0; n < NS; ++n) {
                float e = __expf(dt * Aa[n]);
                h[n] = fmaf(h[n], e, du * Bv[n]);
                p[n] = h[n] * Cv[n];
            }
        }
#pragma unroll
        for (int s = 8; s >= 1; s >>= 1)
#pragma unroll
            for (int n = 0; n < 8; ++n)
                if (n < s) p[n] = p[n] + p[n + s];
        float y = fmaf(Dd, u, p[0]);

        int lg = l0 + l;
        int pos;
        if      (k == 0) pos = lg;
        else if (k == 1) pos = (lg % H_SZ) * W_SZ + (lg / H_SZ);
        else if (k == 2) pos = L_SZ - 1 - lg;
        else { int j = L_SZ - 1 - lg; pos = (j % H_SZ) * W_SZ + (j / H_SZ); }
        ypre_b[(size_t)(b * L_SZ + pos) * CIN + k * DI + d] = f2b(y);
    }
}

// ---------------------------------------------------------------------------
// LayerNorm over CIN=768; bf16 in, bf16 out (stats in fp32).
// ---------------------------------------------------------------------------
__global__ __launch_bounds__(256) void layernorm_bf16(
        const ushort* __restrict__ y, ushort* __restrict__ yb,
        const float* __restrict__ w, const float* __restrict__ bg) {
    int wave = threadIdx.x >> 6, lane = threadIdx.x & 63;
    int tok = blockIdx.x * 4 + wave;
    const ushort* row = &y[(size_t)tok * CIN];
    ushort* rowo = &yb[(size_t)tok * CIN];
    float v[12];
    float s = 0.f;
#pragma unroll
    for (int i = 0; i < 12; ++i) { v[i] = b2f(row[lane + i * 64]); s += v[i]; }
#pragma unroll
    for (int off = 32; off >= 1; off >>= 1) s += __shfl_xor(s, off, 64);
    float mu = s * (1.f / CIN);
    float s2 = 0.f;
#pragma unroll
    for (int i = 0; i < 12; ++i) { float t = v[i] - mu; s2 += t * t; }
#pragma unroll
    for (int off = 32; off >= 1; off >>= 1) s2 += __shfl_xor(s2, off, 64);
    float rstd = rsqrtf(s2 * (1.f / CIN) + 1e-5f);
#pragma unroll
    for (int i = 0; i < 12; ++i)
        rowo[lane + i * 64] =
            f2b((v[i] - mu) * rstd * w[lane + i * 64] + bg[lane + i * 64]);
}

// ---------------------------------------------------------------------------
extern "C" void kernel_launch(void* const* d_in, const int* in_sizes, int n_in,
                              void* d_out, int out_size, void* d_ws, size_t ws_size,
                              hipStream_t stream) {
    const float* x    = (const float*)d_in[0];
    const float* inw  = (const float*)d_in[1];
    const float* cw   = (const float*)d_in[2];
    const float* cb   = (const float*)d_in[3];
    const float* xpw  = (const float*)d_in[4];
    const float* dtw  = (const float*)d_in[5];
    const float* dtb  = (const float*)d_in[6];
    const float* alog = (const float*)d_in[7];
    const float* Dsp  = (const float*)d_in[8];
    const float* lnw  = (const float*)d_in[9];
    const float* lnb  = (const float*)d_in[10];
    const float* outw = (const float*)d_in[11];
    float* out = (float*)d_out;

    float* ws = (float*)d_ws;
    const size_t SZ_BIG = (size_t)MTOK * CIN;            // 3,538,944
    const size_t SCAN_SL = (size_t)8 * NC * DI * NS;     // 3,538,944 (CL=16)
    float* xz    = ws;
    float* xsbf  = xz  + SZ_BIG;
    float* dts   = xsbf + SZ_BIG / 2;
    float* xdbl  = dts + SZ_BIG;
    float* Ebuf  = xdbl + (size_t)8 * L_SZ * XD;
    float* Sbuf  = Ebuf + SCAN_SL;
    float* Hst   = Sbuf + SCAN_SL;
    float* Pbuf  = Hst + SCAN_SL;                        // 8*NC*DI fp32
    uint*  bar   = (uint*)(Pbuf + (size_t)8 * NC * DI);  // 2 uints
    // overlays (strictly sequential producer/consumer):
    ushort* xzb    = (ushort*)xz;
    ushort* xsb    = (ushort*)xsbf;
    ushort* dtsb   = (ushort*)dts;
    ushort* ypre_b = (ushort*)xz;
    ushort* ynrm_b = (ushort*)dts;

    // 1. in-proj GEMM (TM=64: 864 blocks, 2x parallelism vs TM=128)
    gemm_tn<64, 64, false, true><<<dim3(CIN / 64, MTOK / 64), 256, 0, stream>>>(
        x, inw, xzb, MTOK, CIN, 384);
    // 2. depthwise conv + SiLU + scatter
    conv_silu_scatter<<<(B_SZ * H_SZ * W_SZ * 96) / 256, 256, 0, stream>>>(xzb, cw, cb, xsb);
    // 3. fused MFMA x-projection + dt-projection
    xproj_dt_mfma<<<dim3(L_SZ / 32, 8), 384, 0, stream>>>(xsb, xpw, dtw, dtb, xdbl, dtsb);

    // 4. scan: fused single-kernel path if all blocks fit co-resident
    int maxb = 0;
    hipError_t oe = hipOccupancyMaxActiveBlocksPerMultiprocessor(
        &maxb, scan_fused, 192, 0);
    if (oe == hipSuccess && maxb * 256 >= 8 * NC) {
        hipMemsetAsync(bar, 0, 2 * sizeof(uint), stream);
        scan_fused<<<8 * NC, 192, 0, stream>>>(
            dtsb, xsb, xdbl, alog, Ebuf, Sbuf, Pbuf, Hst, Dsp, ypre_b, bar);
    } else {
        scan_passA<<<8 * NC, 192, 0, stream>>>(dtsb, xsb, xdbl, alog, Ebuf, Sbuf, Pbuf);
        scan_passB<<<(8 * DI * 4) / 64, 64, 0, stream>>>(Ebuf, Sbuf, Pbuf, Hst);
        scan_passC<<<8 * NC, 192, 0, stream>>>(dtsb, xsb, xdbl, alog, Hst, Dsp, ypre_b);
    }
    // 5. LayerNorm
    layernorm_bf16<<<MTOK / 4, 256, 0, stream>>>(ypre_b, ynrm_b, lnw, lnb);
    // 6. out-proj GEMM (TN=32: 864 blocks, 2x parallelism vs TN=64)
    gemm_tn<64, 32, true, false><<<dim3(384 / 32, MTOK / 64), 256, 0, stream>>>(
        ynrm_b, outw, out, MTOK, 384, CIN);
}

// Round 9
// 177.100 us; speedup vs baseline: 1.0101x; 1.0101x over previous
//
#include <hip/hip_runtime.h>
#include <hip/hip_bf16.h>

#define B_SZ   2
#define H_SZ   48
#define W_SZ   48
#define L_SZ   2304          // H*W
#define CIN    768           // C_INNER
#define KG     4
#define DI     192           // D_IN (channels per direction)
#define NS     16            // N_STATE
#define RR     12            // R_RANK
#define XD     44            // RR + 2*NS
#define MTOK   4608          // B*L
#define CL     16            // scan chunk length
#define NC     144           // L / CL
#define NXF    (MTOK * 384)  // x elems (fp32) = 1,769,472
#define NWF    (CIN * 384)   // in_proj / out_proj weight elems = 294,912

typedef __attribute__((ext_vector_type(8))) short short8;
typedef __attribute__((ext_vector_type(4))) float f32x4;

__device__ inline ushort f2b(float f) {
    uint u = __builtin_bit_cast(uint, f);
    u = (u + 0x7FFF + ((u >> 16) & 1)) >> 16;   // RNE to bf16
    return (ushort)u;
}
__device__ inline float b2f(ushort b) {
    uint u = ((uint)b) << 16;
    return __builtin_bit_cast(float, u);
}
__device__ inline short8 f2b8(float4 a, float4 b) {
    short8 r;
    r[0] = (short)f2b(a.x); r[1] = (short)f2b(a.y);
    r[2] = (short)f2b(a.z); r[3] = (short)f2b(a.w);
    r[4] = (short)f2b(b.x); r[5] = (short)f2b(b.y);
    r[6] = (short)f2b(b.z); r[7] = (short)f2b(b.w);
    return r;
}

// ---------------------------------------------------------------------------
// One-shot fp32 -> bf16 conversion of x, in_proj_w, out_proj_w.
// 2304 blocks x 256 threads, 4 elems/thread.
// ---------------------------------------------------------------------------
__global__ __launch_bounds__(256) void to_bf16_3(
        const float* __restrict__ x, const float* __restrict__ inw,
        const float* __restrict__ outw, ushort* __restrict__ xb,
        ushort* __restrict__ inwb, ushort* __restrict__ outwb) {
    int i4 = (blockIdx.x * 256 + threadIdx.x) * 4;
    const float* src; ushort* dst; int off;
    if (i4 < NXF)             { src = x;    dst = xb;    off = i4; }
    else if (i4 < NXF + NWF)  { src = inw;  dst = inwb;  off = i4 - NXF; }
    else                      { src = outw; dst = outwb; off = i4 - NXF - NWF; }
    float4 v = *(const float4*)&src[off];
    ushort4 u = {f2b(v.x), f2b(v.y), f2b(v.z), f2b(v.w)};
    *(ushort4*)&dst[off] = u;
}

// ---------------------------------------------------------------------------
// Software grid barrier (device scope).
// ---------------------------------------------------------------------------
__device__ inline void gridbar(uint* bar, uint nb) {
    __syncthreads();
    if (threadIdx.x == 0) {
        uint g = __hip_atomic_load(&bar[1], __ATOMIC_RELAXED, __HIP_MEMORY_SCOPE_AGENT);
        uint a = __hip_atomic_fetch_add(&bar[0], 1u, __ATOMIC_ACQ_REL, __HIP_MEMORY_SCOPE_AGENT);
        if (a == nb - 1u) {
            __hip_atomic_store(&bar[0], 0u, __ATOMIC_RELAXED, __HIP_MEMORY_SCOPE_AGENT);
            __hip_atomic_store(&bar[1], g + 1u, __ATOMIC_RELEASE, __HIP_MEMORY_SCOPE_AGENT);
        } else {
            while (__hip_atomic_load(&bar[1], __ATOMIC_ACQUIRE, __HIP_MEMORY_SCOPE_AGENT) == g) {
                __builtin_amdgcn_s_sleep(8);
            }
        }
    }
    __syncthreads();
}

// ---------------------------------------------------------------------------
// MFMA GEMM: C[M,N] = A[M,K] * Bw[N,K]^T, K-step 64. A and B both bf16 when
// ABF/BBF set (pre-converted); C fp32 or bf16.
// ---------------------------------------------------------------------------
template<int TM, int TN, bool ABF, bool BBF, bool CBF>
__global__ __launch_bounds__(256) void gemm_tn(
        const void* __restrict__ Av, const void* __restrict__ Bw,
        void* __restrict__ Cv, int M, int N, int K) {
    __shared__ ushort As[TM][72];
    __shared__ ushort Bs[TN][72];
    constexpr int MF   = TM / 64;
    constexpr int NF   = TN / 16;
    constexpr int ANUM = TM / 32;
    constexpr int BNUM = TN / 32;
    const int tid  = threadIdx.x;
    const int lane = tid & 63;
    const int wave = tid >> 6;
    const int wrow = wave * (MF * 16);
    const int bm = blockIdx.y * TM, bn = blockIdx.x * TN;
    const int frow = lane & 15;
    const int fk   = (lane >> 4) * 8;
    const int orow = (lane >> 4) * 4;

    f32x4 acc[MF][NF] = {};

    for (int k0 = 0; k0 < K; k0 += 64) {
        short8 aval[ANUM];
#pragma unroll
        for (int i = 0; i < ANUM; ++i) {
            int idx = tid + i * 256;
            int row = idx >> 3, q = idx & 7;
            if (ABF) {
                aval[i] = *(const short8*)&((const ushort*)Av)[(size_t)(bm + row) * K + k0 + q * 8];
            } else {
                const float* ap = &((const float*)Av)[(size_t)(bm + row) * K + k0 + q * 8];
                aval[i] = f2b8(*(const float4*)ap, *(const float4*)(ap + 4));
            }
        }
        short8 bval[BNUM];
#pragma unroll
        for (int i = 0; i < BNUM; ++i) {
            int idx = tid + i * 256;
            int row = idx >> 3, q = idx & 7;
            if (BBF) {
                bval[i] = *(const short8*)&((const ushort*)Bw)[(size_t)(bn + row) * K + k0 + q * 8];
            } else {
                const float* bp = &((const float*)Bw)[(size_t)(bn + row) * K + k0 + q * 8];
                bval[i] = f2b8(*(const float4*)bp, *(const float4*)(bp + 4));
            }
        }

        __syncthreads();
#pragma unroll
        for (int i = 0; i < ANUM; ++i) {
            int idx = tid + i * 256;
            *(short8*)&As[idx >> 3][(idx & 7) * 8] = aval[i];
        }
#pragma unroll
        for (int i = 0; i < BNUM; ++i) {
            int idx = tid + i * 256;
            *(short8*)&Bs[idx >> 3][(idx & 7) * 8] = bval[i];
        }
        __syncthreads();

#pragma unroll
        for (int hf = 0; hf < 2; ++hf) {
            short8 af[MF], bf[NF];
#pragma unroll
            for (int mi = 0; mi < MF; ++mi)
                af[mi] = *(const short8*)&As[wrow + mi * 16 + frow][hf * 32 + fk];
#pragma unroll
            for (int ni = 0; ni < NF; ++ni)
                bf[ni] = *(const short8*)&Bs[ni * 16 + frow][hf * 32 + fk];
#pragma unroll
            for (int mi = 0; mi < MF; ++mi)
#pragma unroll
                for (int ni = 0; ni < NF; ++ni)
                    acc[mi][ni] = __builtin_amdgcn_mfma_f32_16x16x32_bf16(
                                      af[mi], bf[ni], acc[mi][ni], 0, 0, 0);
        }
    }

#pragma unroll
    for (int mi = 0; mi < MF; ++mi) {
        int rbase = bm + wrow + mi * 16 + orow;
#pragma unroll
        for (int ni = 0; ni < NF; ++ni) {
            int col = bn + ni * 16 + frow;
#pragma unroll
            for (int r = 0; r < 4; ++r) {
                if (CBF)
                    ((ushort*)Cv)[(size_t)(rbase + r) * N + col] = f2b(acc[mi][ni][r]);
                else
                    ((float*)Cv)[(size_t)(rbase + r) * N + col] = acc[mi][ni][r];
            }
        }
    }
}

// ---------------------------------------------------------------------------
// Depthwise 3x3 conv + bias + SiLU, 8 channels/thread, vectorized.
// ---------------------------------------------------------------------------
__global__ __launch_bounds__(256) void conv_silu_scatter(
        const ushort* __restrict__ xzb, const float* __restrict__ cw,
        const float* __restrict__ cb, ushort* __restrict__ xsb) {
    int g = blockIdx.x * 256 + threadIdx.x;     // 442368 total
    int c8 = g % 96;
    int pos = g / 96;
    int w = pos % W_SZ;
    int h = (pos / W_SZ) % H_SZ;
    int b = pos / (W_SZ * H_SZ);
    int c0 = c8 * 8;

    float wt[72];
    const float* cwp = &cw[c0 * 9];
#pragma unroll
    for (int i = 0; i < 18; ++i) {
        float4 v = *(const float4*)(cwp + i * 4);
        wt[i * 4 + 0] = v.x; wt[i * 4 + 1] = v.y;
        wt[i * 4 + 2] = v.z; wt[i * 4 + 3] = v.w;
    }
    float acc[8];
#pragma unroll
    for (int j = 0; j < 8; ++j) acc[j] = cb[c0 + j];

#pragma unroll
    for (int dh = -1; dh <= 1; ++dh) {
        int hh = h + dh;
        if (hh < 0 || hh >= H_SZ) continue;
#pragma unroll
        for (int dw = -1; dw <= 1; ++dw) {
            int ww = w + dw;
            if (ww < 0 || ww >= W_SZ) continue;
            int tap = (dh + 1) * 3 + (dw + 1);
            short8 xv = *(const short8*)&xzb[(size_t)((b * H_SZ + hh) * W_SZ + ww) * CIN + c0];
#pragma unroll
            for (int j = 0; j < 8; ++j)
                acc[j] = fmaf(b2f((ushort)xv[j]), wt[j * 9 + tap], acc[j]);
        }
    }

    float s[8];
#pragma unroll
    for (int j = 0; j < 8; ++j)
        s[j] = acc[j] * __builtin_amdgcn_rcpf(1.f + __expf(-acc[j]));   // SiLU

    int k = c0 / DI, d = c0 % DI;
    int lrow = h * W_SZ + w;
    int lcol = w * H_SZ + h;
    int l;
    if      (k == 0) l = lrow;
    else if (k == 1) l = lcol;
    else if (k == 2) l = L_SZ - 1 - lrow;
    else             l = L_SZ - 1 - lcol;
    float4 lo = {s[0], s[1], s[2], s[3]}, hi = {s[4], s[5], s[6], s[7]};
    *(short8*)&xsb[(size_t)((b * KG + k) * L_SZ + l) * DI + d] = f2b8(lo, hi);
}

// ---------------------------------------------------------------------------
// MFMA fused x-projection + dt-projection (32-token tiles, 384 threads).
// ---------------------------------------------------------------------------
__global__ __launch_bounds__(384) void xproj_dt_mfma(
        const ushort* __restrict__ xsb, const float* __restrict__ xpw,
        const float* __restrict__ dtw, const float* __restrict__ dtb,
        float* __restrict__ xdbl, ushort* __restrict__ dts_b) {
    __shared__ ushort Ws[48][200];
    __shared__ ushort Wd[192][40];
    __shared__ ushort dsh[32][40];

    const int tid  = threadIdx.x;
    const int lane = tid & 63;
    const int wave = tid >> 6;        // 0..5
    const int bm = blockIdx.x * 32;
    const int bk = blockIdx.y;
    const int k  = bk & 3;
    const int frow = lane & 15;
    const int fk   = (lane >> 4) * 8;
    const int orow = (lane >> 4) * 4;
    const int rg = wave & 1;
    const int cg = wave >> 1;

#pragma unroll
    for (int i = 0; i < 6; ++i) {
        int idx = tid + i * 384;
        int row = idx / 48, g = idx % 48;
        ushort4 u = {0, 0, 0, 0};
        if (row < XD) {
            float4 v = *(const float4*)&xpw[((size_t)(k * XD) + row) * 192 + g * 4];
            u.x = f2b(v.x); u.y = f2b(v.y); u.z = f2b(v.z); u.w = f2b(v.w);
        }
        *(ushort4*)&Ws[row][g * 4] = u;
    }
#pragma unroll
    for (int i = 0; i < 3; ++i) {
        int idx = tid + i * 384;
        if (idx < 960) {
            float4 z = {0.f, 0.f, 0.f, 0.f};
            *(float4*)&Wd[idx / 5][(idx % 5) * 8] = z;
        } else if (idx < 1120) {
            int j = idx - 960;
            float4 z = {0.f, 0.f, 0.f, 0.f};
            *(float4*)&dsh[j / 5][(j % 5) * 8] = z;
        }
    }
    __syncthreads();

#pragma unroll
    for (int i = 0; i < 6; ++i) {
        int idx = tid + i * 384;
        int row = idx / RR, c = idx % RR;
        Wd[row][c] = f2b(dtw[((size_t)(k * DI) + row) * RR + c]);
    }

    f32x4 acc1 = {};
    const ushort* arow = &xsb[(size_t)(bk * L_SZ + bm + rg * 16 + frow) * DI];
#pragma unroll
    for (int k0 = 0; k0 < 192; k0 += 32) {
        short8 af = *(const short8*)&arow[k0 + fk];
        short8 bv = *(const short8*)&Ws[cg * 16 + frow][k0 + fk];
        acc1 = __builtin_amdgcn_mfma_f32_16x16x32_bf16(af, bv, acc1, 0, 0, 0);
    }

    {
        int col = cg * 16 + frow;
#pragma unroll
        for (int r = 0; r < 4; ++r) {
            float v = acc1[r];
            int row = rg * 16 + orow + r;
            if (col >= RR && col < XD)
                xdbl[(size_t)(bk * L_SZ + bm + row) * XD + col] = v;
            if (cg == 0 && col < RR)
                dsh[row][col] = f2b(v);
        }
    }
    __syncthreads();

#pragma unroll
    for (int t = 0; t < 2; ++t) {
        int d = (wave * 2 + t) * 16 + frow;
        short8 bv = *(const short8*)&Wd[d][fk];
        float bias = dtb[k * DI + d];
#pragma unroll
        for (int rg2 = 0; rg2 < 2; ++rg2) {
            short8 af2 = *(const short8*)&dsh[rg2 * 16 + frow][fk];
            f32x4 a2 = {};
            a2 = __builtin_amdgcn_mfma_f32_16x16x32_bf16(af2, bv, a2, 0, 0, 0);
#pragma unroll
            for (int r = 0; r < 4; ++r) {
                float a = a2[r] + bias;
                float sp = fmaxf(a, 0.f) + __logf(1.f + __expf(-fabsf(a)));
                dts_b[(size_t)(bk * L_SZ + bm + rg2 * 16 + orow + r) * DI + d] = f2b(sp);
            }
        }
    }
}

// ---------------------------------------------------------------------------
// FUSED four-phase scan+LN in ONE kernel via software grid barriers.
// Phases A/B/C as proven; phase D = LayerNorm (4 tokens per block).
// ---------------------------------------------------------------------------
__global__ __launch_bounds__(192, 4) void scan_fused(
        const ushort* __restrict__ dts_b, const ushort* __restrict__ xsb,
        const float* __restrict__ xdbl, const float* __restrict__ A_logs,
        float* __restrict__ Ebuf, float* __restrict__ Sbuf,
        float* __restrict__ Pbuf, float* __restrict__ Hstart,
        const float* __restrict__ Ds, ushort* __restrict__ ypre_b,
        const float* __restrict__ lnw, const float* __restrict__ lnb,
        ushort* __restrict__ ynrm_b, uint* __restrict__ bar) {
    const int blk = blockIdx.x;
    const int bk = blk / NC, ch = blk % NC;
    const int d = threadIdx.x, k = bk % KG, b = bk / KG;
    const int l0 = ch * CL;

    __shared__ float bsh[CL][NS];
    __shared__ float csh[CL][NS];
    __shared__ float red[2][3];
    for (int t = threadIdx.x; t < CL * NS; t += 192) {
        int l = t / NS, n = t % NS;
        const float* row = &xdbl[(size_t)(bk * L_SZ + l0 + l) * XD];
        bsh[l][n] = row[RR + n];
        csh[l][n] = row[RR + NS + n];
    }
    __syncthreads();

    // ---------------- phase A ---------------------------------------------
    {
        float Aa[NS], S[NS];
        const float* ar = &A_logs[(size_t)(k * DI + d) * NS];
        bool fast = true;
#pragma unroll
        for (int n = 0; n < NS; ++n) {
            Aa[n] = -__expf(ar[n]);
            S[n] = 0.f;
            fast = fast && (fabsf(Aa[n] + (float)(n + 1)) < 1e-4f * (n + 1));
        }
        float* sp = &Sbuf[(size_t)((bk * NC + ch) * DI + d) * NS];
        if (fast) {
            float P = 1.f;
#pragma unroll
            for (int l = 0; l < CL; ++l) {
                float dt = b2f(dts_b[(size_t)(bk * L_SZ + l0 + l) * DI + d]);
                float u  = b2f(xsb [(size_t)(bk * L_SZ + l0 + l) * DI + d]);
                float du = dt * u;
                float4 b0 = *(const float4*)&bsh[l][0];
                float4 b1 = *(const float4*)&bsh[l][4];
                float4 b2 = *(const float4*)&bsh[l][8];
                float4 b3 = *(const float4*)&bsh[l][12];
                float Bv[NS] = {b0.x,b0.y,b0.z,b0.w, b1.x,b1.y,b1.z,b1.w,
                                b2.x,b2.y,b2.z,b2.w, b3.x,b3.y,b3.z,b3.w};
                float e1 = __expf(-dt);
                P *= e1;
                float e = e1;
                S[0] = fmaf(S[0], e, du * Bv[0]);
#pragma unroll
                for (int n = 1; n < NS; ++n) {
                    e *= e1;
                    S[n] = fmaf(S[n], e, du * Bv[n]);
                }
            }
            Pbuf[(size_t)(bk * NC + ch) * DI + d] = P;
#pragma unroll
            for (int q = 0; q < 4; ++q) {
                float4 v = {S[q*4], S[q*4+1], S[q*4+2], S[q*4+3]};
                *(float4*)&sp[q * 4] = v;
            }
        } else {
            float E[NS];
#pragma unroll
            for (int n = 0; n < NS; ++n) E[n] = 1.f;
#pragma unroll 8
            for (int l = 0; l < CL; ++l) {
                float dt = b2f(dts_b[(size_t)(bk * L_SZ + l0 + l) * DI + d]);
                float u  = b2f(xsb [(size_t)(bk * L_SZ + l0 + l) * DI + d]);
                float du = dt * u;
                float4 b0 = *(const float4*)&bsh[l][0];
                float4 b1 = *(const float4*)&bsh[l][4];
                float4 b2 = *(const float4*)&bsh[l][8];
                float4 b3 = *(const float4*)&bsh[l][12];
                float Bv[NS] = {b0.x,b0.y,b0.z,b0.w, b1.x,b1.y,b1.z,b1.w,
                                b2.x,b2.y,b2.z,b2.w, b3.x,b3.y,b3.z,b3.w};
#pragma unroll
                for (int n = 0; n < NS; ++n) {
                    float e = __expf(dt * Aa[n]);
                    E[n] *= e;
                    S[n] = fmaf(S[n], e, du * Bv[n]);
                }
            }
            Pbuf[(size_t)(bk * NC + ch) * DI + d] = -1.f;
            float* ep = &Ebuf[(size_t)((bk * NC + ch) * DI + d) * NS];
#pragma unroll
            for (int q = 0; q < 4; ++q) {
                float4 ve = {E[q*4], E[q*4+1], E[q*4+2], E[q*4+3]};
                float4 vs = {S[q*4], S[q*4+1], S[q*4+2], S[q*4+3]};
                *(float4*)&ep[q * 4] = ve;
                *(float4*)&sp[q * 4] = vs;
            }
        }
    }

    gridbar(bar, gridDim.x);

    // ---------------- phase B (first 6144 threads) ------------------------
    {
        constexpr int P = 8;
        int t = blk * 192 + threadIdx.x;
        if (t < 8 * DI * 4) {
            int bkB = t / (DI * 4);
            int dn = (t % (DI * 4)) * 4;
            int dB = dn >> 4;
            int n0 = dn & 15;
            const size_t stride = (size_t)DI * NS;
            size_t off = (size_t)(bkB * NC) * stride + dn;
            const float* pb = &Pbuf[(size_t)(bkB * NC) * DI + dB];

            float4 h = {0.f, 0.f, 0.f, 0.f};
            bool fastu = (pb[0] >= 0.f);

            if (fastu) {
                float  pA[P], pB2[P];
                float4 sA[P], sB[P];
                size_t offL = off;
                int    cP   = 0;
#pragma unroll
                for (int j = 0; j < P; ++j) {
                    pA[j] = pb[(size_t)(cP + j) * DI];
                    sA[j] = *(const float4*)&Sbuf[offL + (size_t)j * stride];
                }
                offL += (size_t)P * stride; cP += P;

                for (int c = 0; c < NC; c += 2 * P) {
#pragma unroll
                    for (int j = 0; j < P; ++j) {
                        pB2[j] = pb[(size_t)(cP + j) * DI];
                        sB[j] = *(const float4*)&Sbuf[offL + (size_t)j * stride];
                    }
                    offL += (size_t)P * stride; cP += P;

#pragma unroll
                    for (int j = 0; j < P; ++j) {
                        *(float4*)&Hstart[off + (size_t)j * stride] = h;
                        float Pv = pA[j];
                        float P2 = Pv * Pv, P3 = P2 * Pv;
                        float P4 = P2 * P2, P8 = P4 * P4;
                        float base = Pv * ((n0 & 4) ? P4 : 1.f) * ((n0 & 8) ? P8 : 1.f);
                        h.x = fmaf(base,      h.x, sA[j].x);
                        h.y = fmaf(base * Pv, h.y, sA[j].y);
                        h.z = fmaf(base * P2, h.z, sA[j].z);
                        h.w = fmaf(base * P3, h.w, sA[j].w);
                    }
                    off += (size_t)P * stride;

                    if (c + 2 * P < NC) {
#pragma unroll
                        for (int j = 0; j < P; ++j) {
                            pA[j] = pb[(size_t)(cP + j) * DI];
                            sA[j] = *(const float4*)&Sbuf[offL + (size_t)j * stride];
                        }
                    }
                    offL += (size_t)P * stride; cP += P;

#pragma unroll
                    for (int j = 0; j < P; ++j) {
                        *(float4*)&Hstart[off + (size_t)j * stride] = h;
                        float Pv = pB2[j];
                        float P2 = Pv * Pv, P3 = P2 * Pv;
                        float P4 = P2 * P2, P8 = P4 * P4;
                        float base = Pv * ((n0 & 4) ? P4 : 1.f) * ((n0 & 8) ? P8 : 1.f);
                        h.x = fmaf(base,      h.x, sB[j].x);
                        h.y = fmaf(base * Pv, h.y, sB[j].y);
                        h.z = fmaf(base * P2, h.z, sB[j].z);
                        h.w = fmaf(base * P3, h.w, sB[j].w);
                    }
                    off += (size_t)P * stride;
                }
            } else {
                float4 eA[P], sA[P], eB[P], sB[P];
                size_t offL = off;
#pragma unroll
                for (int j = 0; j < P; ++j) {
                    eA[j] = *(const float4*)&Ebuf[offL + (size_t)j * stride];
                    sA[j] = *(const float4*)&Sbuf[offL + (size_t)j * stride];
                }
                offL += (size_t)P * stride;

                for (int c = 0; c < NC; c += 2 * P) {
#pragma unroll
                    for (int j = 0; j < P; ++j) {
                        eB[j] = *(const float4*)&Ebuf[offL + (size_t)j * stride];
                        sB[j] = *(const float4*)&Sbuf[offL + (size_t)j * stride];
                    }
                    offL += (size_t)P * stride;

#pragma unroll
                    for (int j = 0; j < P; ++j) {
                        *(float4*)&Hstart[off + (size_t)j * stride] = h;
                        h.x = fmaf(eA[j].x, h.x, sA[j].x);
                        h.y = fmaf(eA[j].y, h.y, sA[j].y);
                        h.z = fmaf(eA[j].z, h.z, sA[j].z);
                        h.w = fmaf(eA[j].w, h.w, sA[j].w);
                    }
                    off += (size_t)P * stride;

                    if (c + 2 * P < NC) {
#pragma unroll
                        for (int j = 0; j < P; ++j) {
                            eA[j] = *(const float4*)&Ebuf[offL + (size_t)j * stride];
                            sA[j] = *(const float4*)&Sbuf[offL + (size_t)j * stride];
                        }
                    }
                    offL += (size_t)P * stride;

#pragma unroll
                    for (int j = 0; j < P; ++j) {
                        *(float4*)&Hstart[off + (size_t)j * stride] = h;
                        h.x = fmaf(eB[j].x, h.x, sB[j].x);
                        h.y = fmaf(eB[j].y, h.y, sB[j].y);
                        h.z = fmaf(eB[j].z, h.z, sB[j].z);
                        h.w = fmaf(eB[j].w, h.w, sB[j].w);
                    }
                    off += (size_t)P * stride;
                }
            }
        }
    }

    gridbar(bar, gridDim.x);

    // ---------------- phase C ---------------------------------------------
    {
        float Aa[NS], h[NS];
        const float* ar = &A_logs[(size_t)(k * DI + d) * NS];
        const float* hp = &Hstart[(size_t)((bk * NC + ch) * DI + d) * NS];
        bool fast = true;
#pragma unroll
        for (int n = 0; n < NS; ++n) {
            Aa[n] = -__expf(ar[n]);
            h[n] = hp[n];
            fast = fast && (fabsf(Aa[n] + (float)(n + 1)) < 1e-4f * (n + 1));
        }
        float Dd = Ds[k * DI + d];

#pragma unroll 8
        for (int l = 0; l < CL; ++l) {
            float dt = b2f(dts_b[(size_t)(bk * L_SZ + l0 + l) * DI + d]);
            float u  = b2f(xsb [(size_t)(bk * L_SZ + l0 + l) * DI + d]);
            float du = dt * u;
            float4 b0 = *(const float4*)&bsh[l][0];
            float4 b1 = *(const float4*)&bsh[l][4];
            float4 b2 = *(const float4*)&bsh[l][8];
            float4 b3 = *(const float4*)&bsh[l][12];
            float Bv[NS] = {b0.x,b0.y,b0.z,b0.w, b1.x,b1.y,b1.z,b1.w,
                            b2.x,b2.y,b2.z,b2.w, b3.x,b3.y,b3.z,b3.w};
            float4 c0 = *(const float4*)&csh[l][0];
            float4 c1 = *(const float4*)&csh[l][4];
            float4 c2 = *(const float4*)&csh[l][8];
            float4 c3 = *(const float4*)&csh[l][12];
            float Cv[NS] = {c0.x,c0.y,c0.z,c0.w, c1.x,c1.y,c1.z,c1.w,
                            c2.x,c2.y,c2.z,c2.w, c3.x,c3.y,c3.z,c3.w};
            float p[NS];
            if (fast) {
                float e1 = __expf(-dt);
                float e = e1;
                h[0] = fmaf(h[0], e, du * Bv[0]);
                p[0] = h[0] * Cv[0];
#pragma unroll
                for (int n = 1; n < NS; ++n) {
                    e *= e1;
                    h[n] = fmaf(h[n], e, du * Bv[n]);
                    p[n] = h[n] * Cv[n];
                }
            } else {
#pragma unroll
                for (int n = 0; n < NS; ++n) {
                    float e = __expf(dt * Aa[n]);
                    h[n] = fmaf(h[n], e, du * Bv[n]);
                    p[n] = h[n] * Cv[n];
                }
            }
#pragma unroll
            for (int s = 8; s >= 1; s >>= 1)
#pragma unroll
                for (int n = 0; n < 8; ++n)
                    if (n < s) p[n] = p[n] + p[n + s];
            float y = fmaf(Dd, u, p[0]);

            int lg = l0 + l;
            int pos;
            if      (k == 0) pos = lg;
            else if (k == 1) pos = (lg % H_SZ) * W_SZ + (lg / H_SZ);
            else if (k == 2) pos = L_SZ - 1 - lg;
            else { int j = L_SZ - 1 - lg; pos = (j % H_SZ) * W_SZ + (j / H_SZ); }
            ypre_b[(size_t)(b * L_SZ + pos) * CIN + k * DI + d] = f2b(y);
        }
    }

    gridbar(bar, gridDim.x);

    // ---------------- phase D: LayerNorm, 4 tokens per block --------------
    {
        int lane = threadIdx.x & 63, wv = threadIdx.x >> 6;
        int i4 = threadIdx.x * 4;                 // 0..764
        float4 w4 = *(const float4*)&lnw[i4];
        float4 g4 = *(const float4*)&lnb[i4];
        for (int j = 0; j < 4; ++j) {
            int tok = blk * 4 + j;
            ushort4 rv = *(const ushort4*)&ypre_b[(size_t)tok * CIN + i4];
            float v0 = b2f(rv.x), v1 = b2f(rv.y), v2 = b2f(rv.z), v3 = b2f(rv.w);
            float s1 = v0 + v1 + v2 + v3;
            float s2 = v0*v0 + v1*v1 + v2*v2 + v3*v3;
#pragma unroll
            for (int off = 32; off >= 1; off >>= 1) {
                s1 += __shfl_xor(s1, off, 64);
                s2 += __shfl_xor(s2, off, 64);
            }
            if (lane == 0) { red[0][wv] = s1; red[1][wv] = s2; }
            __syncthreads();
            float ts1 = red[0][0] + red[0][1] + red[0][2];
            float ts2 = red[1][0] + red[1][1] + red[1][2];
            float mu = ts1 * (1.f / CIN);
            float rstd = rsqrtf(ts2 * (1.f / CIN) - mu * mu + 1e-5f);
            ushort4 o;
            o.x = f2b((v0 - mu) * rstd * w4.x + g4.x);
            o.y = f2b((v1 - mu) * rstd * w4.y + g4.y);
            o.z = f2b((v2 - mu) * rstd * w4.z + g4.z);
            o.w = f2b((v3 - mu) * rstd * w4.w + g4.w);
            *(ushort4*)&ynrm_b[(size_t)tok * CIN + i4] = o;
            __syncthreads();
        }
    }
}

// ---------------------------------------------------------------------------
// Fallback separate scan kernels (proven round-6 versions).
// ---------------------------------------------------------------------------
__global__ __launch_bounds__(192) void scan_passA(
        const ushort* __restrict__ dts_b, const ushort* __restrict__ xsb,
        const float* __restrict__ xdbl, const float* __restrict__ A_logs,
        float* __restrict__ Ebuf, float* __restrict__ Sbuf,
        float* __restrict__ Pbuf) {
    int blk = blockIdx.x;
    int bk = blk / NC, ch = blk % NC;
    int d = threadIdx.x, k = bk % KG;
    int l0 = ch * CL;

    __shared__ float bsh[CL][NS];
    for (int t = threadIdx.x; t < CL * NS; t += 192) {
        int l = t / NS, n = t % NS;
        bsh[l][n] = xdbl[(size_t)(bk * L_SZ + l0 + l) * XD + RR + n];
    }
    __syncthreads();

    float Aa[NS], S[NS];
    const float* ar = &A_logs[(size_t)(k * DI + d) * NS];
    bool fast = true;
#pragma unroll
    for (int n = 0; n < NS; ++n) {
        Aa[n] = -__expf(ar[n]);
        S[n] = 0.f;
        fast = fast && (fabsf(Aa[n] + (float)(n + 1)) < 1e-4f * (n + 1));
    }

    float* sp = &Sbuf[(size_t)((bk * NC + ch) * DI + d) * NS];
    if (fast) {
        float P = 1.f;
#pragma unroll
        for (int l = 0; l < CL; ++l) {
            float dt = b2f(dts_b[(size_t)(bk * L_SZ + l0 + l) * DI + d]);
            float u  = b2f(xsb [(size_t)(bk * L_SZ + l0 + l) * DI + d]);
            float du = dt * u;
            float4 b0 = *(const float4*)&bsh[l][0];
            float4 b1 = *(const float4*)&bsh[l][4];
            float4 b2 = *(const float4*)&bsh[l][8];
            float4 b3 = *(const float4*)&bsh[l][12];
            float Bv[NS] = {b0.x,b0.y,b0.z,b0.w, b1.x,b1.y,b1.z,b1.w,
                            b2.x,b2.y,b2.z,b2.w, b3.x,b3.y,b3.z,b3.w};
            float e1 = __expf(-dt);
            P *= e1;
            float e = e1;
            S[0] = fmaf(S[0], e, du * Bv[0]);
#pragma unroll
            for (int n = 1; n < NS; ++n) {
                e *= e1;
                S[n] = fmaf(S[n], e, du * Bv[n]);
            }
        }
        Pbuf[(size_t)(bk * NC + ch) * DI + d] = P;
#pragma unroll
        for (int q = 0; q < 4; ++q) {
            float4 v = {S[q*4], S[q*4+1], S[q*4+2], S[q*4+3]};
            *(float4*)&sp[q * 4] = v;
        }
    } else {
        float E[NS];
#pragma unroll
        for (int n = 0; n < NS; ++n) E[n] = 1.f;
#pragma unroll 8
        for (int l = 0; l < CL; ++l) {
            float dt = b2f(dts_b[(size_t)(bk * L_SZ + l0 + l) * DI + d]);
            float u  = b2f(xsb [(size_t)(bk * L_SZ + l0 + l) * DI + d]);
            float du = dt * u;
            float4 b0 = *(const float4*)&bsh[l][0];
            float4 b1 = *(const float4*)&bsh[l][4];
            float4 b2 = *(const float4*)&bsh[l][8];
            float4 b3 = *(const float4*)&bsh[l][12];
            float Bv[NS] = {b0.x,b0.y,b0.z,b0.w, b1.x,b1.y,b1.z,b1.w,
                            b2.x,b2.y,b2.z,b2.w, b3.x,b3.y,b3.z,b3.w};
#pragma unroll
            for (int n = 0; n < NS; ++n) {
                float e = __expf(dt * Aa[n]);
                E[n] *= e;
                S[n] = fmaf(S[n], e, du * Bv[n]);
            }
        }
        Pbuf[(size_t)(bk * NC + ch) * DI + d] = -1.f;
        float* ep = &Ebuf[(size_t)((bk * NC + ch) * DI + d) * NS];
#pragma unroll
        for (int q = 0; q < 4; ++q) {
            float4 ve = {E[q*4], E[q*4+1], E[q*4+2], E[q*4+3]};
            float4 vs = {S[q*4], S[q*4+1], S[q*4+2], S[q*4+3]};
            *(float4*)&ep[q * 4] = ve;
            *(float4*)&sp[q * 4] = vs;
        }
    }
}

__global__ __launch_bounds__(64) void scan_passB(
        const float* __restrict__ Ebuf, const float* __restrict__ Sbuf,
        const float* __restrict__ Pbuf, float* __restrict__ Hstart) {
    constexpr int P = 8;
    int t = blockIdx.x * 64 + threadIdx.x;
    int bk = t / (DI * 4);
    int dn = (t % (DI * 4)) * 4;
    int d  = dn >> 4;
    int n0 = dn & 15;
    const size_t stride = (size_t)DI * NS;
    size_t off  = (size_t)(bk * NC) * stride + dn;
    const float* pb = &Pbuf[(size_t)(bk * NC) * DI + d];

    float4 h = {0.f, 0.f, 0.f, 0.f};
    bool fastu = (pb[0] >= 0.f);

    if (fastu) {
        float  pA[P], pB[P];
        float4 sA[P], sB[P];
        size_t offL = off;
        int    cP   = 0;
#pragma unroll
        for (int j = 0; j < P; ++j) {
            pA[j] = pb[(size_t)(cP + j) * DI];
            sA[j] = *(const float4*)&Sbuf[offL + (size_t)j * stride];
        }
        offL += (size_t)P * stride; cP += P;

        for (int c = 0; c < NC; c += 2 * P) {
#pragma unroll
            for (int j = 0; j < P; ++j) {
                pB[j] = pb[(size_t)(cP + j) * DI];
                sB[j] = *(const float4*)&Sbuf[offL + (size_t)j * stride];
            }
            offL += (size_t)P * stride; cP += P;

#pragma unroll
            for (int j = 0; j < P; ++j) {
                *(float4*)&Hstart[off + (size_t)j * stride] = h;
                float Pv = pA[j];
                float P2 = Pv * Pv, P3 = P2 * Pv;
                float P4 = P2 * P2, P8 = P4 * P4;
                float base = Pv * ((n0 & 4) ? P4 : 1.f) * ((n0 & 8) ? P8 : 1.f);
                h.x = fmaf(base,      h.x, sA[j].x);
                h.y = fmaf(base * Pv, h.y, sA[j].y);
                h.z = fmaf(base * P2, h.z, sA[j].z);
                h.w = fmaf(base * P3, h.w, sA[j].w);
            }
            off += (size_t)P * stride;

            if (c + 2 * P < NC) {
#pragma unroll
                for (int j = 0; j < P; ++j) {
                    pA[j] = pb[(size_t)(cP + j) * DI];
                    sA[j] = *(const float4*)&Sbuf[offL + (size_t)j * stride];
                }
            }
            offL += (size_t)P * stride; cP += P;

#pragma unroll
            for (int j = 0; j < P; ++j) {
                *(float4*)&Hstart[off + (size_t)j * stride] = h;
                float Pv = pB[j];
                float P2 = Pv * Pv, P3 = P2 * Pv;
                float P4 = P2 * P2, P8 = P4 * P4;
                float base = Pv * ((n0 & 4) ? P4 : 1.f) * ((n0 & 8) ? P8 : 1.f);
                h.x = fmaf(base,      h.x, sB[j].x);
                h.y = fmaf(base * Pv, h.y, sB[j].y);
                h.z = fmaf(base * P2, h.z, sB[j].z);
                h.w = fmaf(base * P3, h.w, sB[j].w);
            }
            off += (size_t)P * stride;
        }
    } else {
        float4 eA[P], sA[P], eB[P], sB[P];
        size_t offL = off;
#pragma unroll
        for (int j = 0; j < P; ++j) {
            eA[j] = *(const float4*)&Ebuf[offL + (size_t)j * stride];
            sA[j] = *(const float4*)&Sbuf[offL + (size_t)j * stride];
        }
        offL += (size_t)P * stride;

        for (int c = 0; c < NC; c += 2 * P) {
#pragma unroll
            for (int j = 0; j < P; ++j) {
                eB[j] = *(const float4*)&Ebuf[offL + (size_t)j * stride];
                sB[j] = *(const float4*)&Sbuf[offL + (size_t)j * stride];
            }
            offL += (size_t)P * stride;

#pragma unroll
            for (int j = 0; j < P; ++j) {
                *(float4*)&Hstart[off + (size_t)j * stride] = h;
                h.x = fmaf(eA[j].x, h.x, sA[j].x);
                h.y = fmaf(eA[j].y, h.y, sA[j].y);
                h.z = fmaf(eA[j].z, h.z, sA[j].z);
                h.w = fmaf(eA[j].w, h.w, sA[j].w);
            }
            off += (size_t)P * stride;

            if (c + 2 * P < NC) {
#pragma unroll
                for (int j = 0; j < P; ++j) {
                    eA[j] = *(const float4*)&Ebuf[offL + (size_t)j * stride];
                    sA[j] = *(const float4*)&Sbuf[offL + (size_t)j * stride];
                }
            }
            offL += (size_t)P * stride;

#pragma unroll
            for (int j = 0; j < P; ++j) {
                *(float4*)&Hstart[off + (size_t)j * stride] = h;
                h.x = fmaf(eB[j].x, h.x, sB[j].x);
                h.y = fmaf(eB[j].y, h.y, sB[j].y);
                h.z = fmaf(eB[j].z, h.z, sB[j].z);
                h.w = fmaf(eB[j].w, h.w, sB[j].w);
            }
            off += (size_t)P * stride;
        }
    }
}

__global__ __launch_bounds__(192) void scan_passC(
        const ushort* __restrict__ dts_b, const ushort* __restrict__ xsb,
        const float* __restrict__ xdbl, const float* __restrict__ A_logs,
        const float* __restrict__ Hstart, const float* __restrict__ Ds,
        ushort* __restrict__ ypre_b) {
    int blk = blockIdx.x;
    int bk = blk / NC, ch = blk % NC;
    int d = threadIdx.x, k = bk % KG, b = bk / KG;
    int l0 = ch * CL;

    __shared__ float bsh[CL][NS];
    __shared__ float csh[CL][NS];
    for (int t = threadIdx.x; t < CL * NS; t += 192) {
        int l = t / NS, n = t % NS;
        const float* row = &xdbl[(size_t)(bk * L_SZ + l0 + l) * XD];
        bsh[l][n] = row[RR + n];
        csh[l][n] = row[RR + NS + n];
    }
    __syncthreads();

    float Aa[NS], h[NS];
    const float* ar = &A_logs[(size_t)(k * DI + d) * NS];
    const float* hp = &Hstart[(size_t)((bk * NC + ch) * DI + d) * NS];
    bool fast = true;
#pragma unroll
    for (int n = 0; n < NS; ++n) {
        Aa[n] = -__expf(ar[n]);
        h[n] = hp[n];
        fast = fast && (fabsf(Aa[n] + (float)(n + 1)) < 1e-4f * (n + 1));
    }
    float Dd = Ds[k * DI + d];

#pragma unroll 8
    for (int l = 0; l < CL; ++l) {
        float dt = b2f(dts_b[(size_t)(bk * L_SZ + l0 + l) * DI + d]);
        float u  = b2f(xsb [(size_t)(bk * L_SZ + l0 + l) * DI + d]);
        float du = dt * u;
        float4 b0 = *(const float4*)&bsh[l][0];
        float4 b1 = *(const float4*)&bsh[l][4];
        float4 b2 = *(const float4*)&bsh[l][8];
        float4 b3 = *(const float4*)&bsh[l][12];
        float Bv[NS] = {b0.x,b0.y,b0.z,b0.w, b1.x,b1.y,b1.z,b1.w,
                        b2.x,b2.y,b2.z,b2.w, b3.x,b3.y,b3.z,b3.w};
        float4 c0 = *(const float4*)&csh[l][0];
        float4 c1 = *(const float4*)&csh[l][4];
        float4 c2 = *(const float4*)&csh[l][8];
        float4 c3 = *(const float4*)&csh[l][12];
        float Cv[NS] = {c0.x,c0.y,c0.z,c0.w, c1.x,c1.y,c1.z,c1.w,
                        c2.x,c2.y,c2.z,c2.w, c3.x,c3.y,c3.z,c3.w};
        float p[NS];
        if (fast) {
            float e1 = __expf(-dt);
            float e = e1;
            h[0] = fmaf(h[0], e, du * Bv[0]);
            p[0] = h[0] * Cv[0];
#pragma unroll
            for (int n = 1; n < NS; ++n) {
                e *= e1;
                h[n] = fmaf(h[n], e, du * Bv[n]);
                p[n] = h[n] * Cv[n];
            }
        } else {
#pragma unroll
            for (int n = 0; n < NS; ++n) {
                float e = __expf(dt * Aa[n]);
                h[n] = fmaf(h[n], e, du * Bv[n]);
                p[n] = h[n] * Cv[n];
            }
        }
#pragma unroll
        for (int s = 8; s >= 1; s >>= 1)
#pragma unroll
            for (int n = 0; n < 8; ++n)
                if (n < s) p[n] = p[n] + p[n + s];
        float y = fmaf(Dd, u, p[0]);

        int lg = l0 + l;
        int pos;
        if      (k == 0) pos = lg;
        else if (k == 1) pos = (lg % H_SZ) * W_SZ + (lg / H_SZ);
        else if (k == 2) pos = L_SZ - 1 - lg;
        else { int j = L_SZ - 1 - lg; pos = (j % H_SZ) * W_SZ + (j / H_SZ); }
        ypre_b[(size_t)(b * L_SZ + pos) * CIN + k * DI + d] = f2b(y);
    }
}

// ---------------------------------------------------------------------------
// LayerNorm over CIN=768; bf16 in, bf16 out (fallback path only).
// ---------------------------------------------------------------------------
__global__ __launch_bounds__(256) void layernorm_bf16(
        const ushort* __restrict__ y, ushort* __restrict__ yb,
        const float* __restrict__ w, const float* __restrict__ bg) {
    int wave = threadIdx.x >> 6, lane = threadIdx.x & 63;
    int tok = blockIdx.x * 4 + wave;
    const ushort* row = &y[(size_t)tok * CIN];
    ushort* rowo = &yb[(size_t)tok * CIN];
    float v[12];
    float s = 0.f;
#pragma unroll
    for (int i = 0; i < 12; ++i) { v[i] = b2f(row[lane + i * 64]); s += v[i]; }
#pragma unroll
    for (int off = 32; off >= 1; off >>= 1) s += __shfl_xor(s, off, 64);
    float mu = s * (1.f / CIN);
    float s2 = 0.f;
#pragma unroll
    for (int i = 0; i < 12; ++i) { float t = v[i] - mu; s2 += t * t; }
#pragma unroll
    for (int off = 32; off >= 1; off >>= 1) s2 += __shfl_xor(s2, off, 64);
    float rstd = rsqrtf(s2 * (1.f / CIN) + 1e-5f);
#pragma unroll
    for (int i = 0; i < 12; ++i)
        rowo[lane + i * 64] =
            f2b((v[i] - mu) * rstd * w[lane + i * 64] + bg[lane + i * 64]);
}

// ---------------------------------------------------------------------------
extern "C" void kernel_launch(void* const* d_in, const int* in_sizes, int n_in,
                              void* d_out, int out_size, void* d_ws, size_t ws_size,
                              hipStream_t stream) {
    const float* x    = (const float*)d_in[0];
    const float* inw  = (const float*)d_in[1];
    const float* cw   = (const float*)d_in[2];
    const float* cb   = (const float*)d_in[3];
    const float* xpw  = (const float*)d_in[4];
    const float* dtw  = (const float*)d_in[5];
    const float* dtb  = (const float*)d_in[6];
    const float* alog = (const float*)d_in[7];
    const float* Dsp  = (const float*)d_in[8];
    const float* lnw  = (const float*)d_in[9];
    const float* lnb  = (const float*)d_in[10];
    const float* outw = (const float*)d_in[11];
    float* out = (float*)d_out;

    float* ws = (float*)d_ws;
    const size_t SZ_BIG = (size_t)MTOK * CIN;            // 3,538,944
    const size_t SCAN_SL = (size_t)8 * NC * DI * NS;     // 3,538,944 (CL=16)
    float* xz    = ws;
    float* xsbf  = xz  + SZ_BIG;
    float* dts   = xsbf + SZ_BIG / 2;
    float* xdbl  = dts + SZ_BIG;
    float* Ebuf  = xdbl + (size_t)8 * L_SZ * XD;
    float* Sbuf  = Ebuf + SCAN_SL;
    float* Hst   = Sbuf + SCAN_SL;
    float* Pbuf  = Hst + SCAN_SL;                        // 8*NC*DI fp32
    ushort* xb   = (ushort*)(Pbuf + (size_t)8 * NC * DI);// bf16 x (NXF)
    ushort* inwb = xb + NXF;                             // bf16 in_proj_w
    ushort* outwb= inwb + NWF;                           // bf16 out_proj_w
    uint*  bar   = (uint*)(outwb + NWF);                 // 2 uints
    // overlays (strictly sequential producer/consumer):
    ushort* xzb    = (ushort*)xz;
    ushort* xsb    = (ushort*)xsbf;
    ushort* dtsb   = (ushort*)dts;
    ushort* ypre_b = (ushort*)xz;
    ushort* ynrm_b = (ushort*)dts;

    // 0. pre-convert x / in_proj_w / out_proj_w to bf16
    to_bf16_3<<<(NXF + 2 * NWF) / 1024, 256, 0, stream>>>(x, inw, outw, xb, inwb, outwb);
    // 1. in-proj GEMM (all-bf16 staging)
    gemm_tn<64, 64, true, true, true><<<dim3(CIN / 64, MTOK / 64), 256, 0, stream>>>(
        xb, inwb, xzb, MTOK, CIN, 384);
    // 2. depthwise conv + SiLU + scatter
    conv_silu_scatter<<<(B_SZ * H_SZ * W_SZ * 96) / 256, 256, 0, stream>>>(xzb, cw, cb, xsb);
    // 3. fused MFMA x-projection + dt-projection
    xproj_dt_mfma<<<dim3(L_SZ / 32, 8), 384, 0, stream>>>(xsb, xpw, dtw, dtb, xdbl, dtsb);

    // 4. scan (+LN as phase D): fused single-kernel path if co-resident
    int maxb = 0;
    hipError_t oe = hipOccupancyMaxActiveBlocksPerMultiprocessor(
        &maxb, scan_fused, 192, 0);
    if (oe == hipSuccess && maxb * 256 >= 8 * NC) {
        hipMemsetAsync(bar, 0, 2 * sizeof(uint), stream);
        scan_fused<<<8 * NC, 192, 0, stream>>>(
            dtsb, xsb, xdbl, alog, Ebuf, Sbuf, Pbuf, Hst, Dsp, ypre_b,
            lnw, lnb, ynrm_b, bar);
    } else {
        scan_passA<<<8 * NC, 192, 0, stream>>>(dtsb, xsb, xdbl, alog, Ebuf, Sbuf, Pbuf);
        scan_passB<<<(8 * DI * 4) / 64, 64, 0, stream>>>(Ebuf, Sbuf, Pbuf, Hst);
        scan_passC<<<8 * NC, 192, 0, stream>>>(dtsb, xsb, xdbl, alog, Hst, Dsp, ypre_b);
        layernorm_bf16<<<MTOK / 4, 256, 0, stream>>>(ypre_b, ynrm_b, lnw, lnb);
    }
    // 5. out-proj GEMM (all-bf16 staging)
    gemm_tn<64, 32, true, true, false><<<dim3(384 / 32, MTOK / 64), 256, 0, stream>>>(
        ynrm_b, outwb, out, MTOK, 384, CIN);
}